// Round 2
// baseline (55.787 us; speedup 1.0000x reference)
//
#include <hip/hip_runtime.h>
#include <hip/hip_bf16.h>

#define Bdim 4096
#define Ldim 4096
#define Hdim 1024
#define BM 256
#define BN 256
#define BK 64
#define NT (Hdim / BK)   // 16 K-tiles

typedef __attribute__((ext_vector_type(8))) __bf16 bf16x8;
typedef __attribute__((ext_vector_type(4))) float floatx4;

__device__ __forceinline__ unsigned short f2bf(float f) {
  union { __hip_bfloat16 h; unsigned short u; } c;
  c.h = __float2bfloat16(f);
  return c.u;
}

// ---- fused prep: blocks [0,Ldim) do W->bf16 + bias row; [Ldim,+Bdim) X->bf16
__global__ __launch_bounds__(256) void prep_kernel(
    const float* __restrict__ X, const float* __restrict__ E,
    const float* __restrict__ W, const float* __restrict__ b,
    unsigned short* __restrict__ Xb, unsigned short* __restrict__ Wb,
    float* __restrict__ bias) {
  const int blk = blockIdx.x;
  const int t = threadIdx.x;
  if (blk < Ldim) {
    const int row = blk;
    const float4 wv = reinterpret_cast<const float4*>(W + (size_t)row * Hdim)[t];
    const float4 ev = reinterpret_cast<const float4*>(E + (size_t)row * Hdim)[t];
    ushort4 o;
    o.x = f2bf(wv.x); o.y = f2bf(wv.y); o.z = f2bf(wv.z); o.w = f2bf(wv.w);
    reinterpret_cast<ushort4*>(Wb + (size_t)row * Hdim)[t] = o;
    float dot = wv.x * ev.x + wv.y * ev.y + wv.z * ev.z + wv.w * ev.w;
#pragma unroll
    for (int off = 32; off > 0; off >>= 1) dot += __shfl_down(dot, off, 64);
    __shared__ float part[4];
    if ((t & 63) == 0) part[t >> 6] = dot;
    __syncthreads();
    if (t == 0) bias[row] = part[0] + part[1] + part[2] + part[3] + b[row];
  } else {
    const int i = (blk - Ldim) * 256 + t;
    float4 v = reinterpret_cast<const float4*>(X)[i];
    ushort4 o;
    o.x = f2bf(v.x); o.y = f2bf(v.y); o.z = f2bf(v.z); o.w = f2bf(v.w);
    reinterpret_cast<ushort4*>(Xb)[i] = o;
  }
}

// ---- C[B,L] = Xb @ Wb^T + bias -----------------------------------------
// 256x256 tile, BK=64, 8 waves (2M x 4N, each owns 128x64 output).
// m201-exact 8-phase-rate schedule: 4 quadrant-phases per K-tile, each
//   { ds_reads (12/8/4/0), stage (2-4 GLL), s_barrier, lgkmcnt(0),
//     setprio(1), 16 MFMA, setprio(0), s_barrier }
// Staging cadence per tile t (computing buf c=t&1, staging t+1 into c^1):
//   q0: A-h1(t+1), B-h0(t+1)   q1: B-h1(t+1)   q2: --
//   q3: A-h0(t+2) -> buf c  [safe: all buf-c ds_reads complete at q2's
//       post-MFMA barrier]
// Single counted gate per tile at q3: vmcnt(2) -- per-wave outstanding
// there = {leftover A-h0(t+1)} + {Ah1,Bh0,Bh1(t+1)} + {Ah0(t+2)} <= 10;
// gating to 2 completes ALL of tile t+1's data, leaves Ah0(t+2) in flight.
// Next tile's q0 reads buf c^1 only after this gate's barrier. Never
// vmcnt(0) mid-loop.
// LDS swizzle (T2, conflicts=0 measured): k-slot ks (16B) of row r stored
// at ks ^ (r&7); GLL dest linear, global SOURCE pre-swizzled per lane
// (row&7 == lane>>3 under the GLL lane pattern), reads apply the same XOR.
__global__ __launch_bounds__(512, 2) void gemm_bias_kernel(
    const unsigned short* __restrict__ A,   // [Bdim][Hdim] bf16 bits
    const unsigned short* __restrict__ Bw,  // [Ldim][Hdim] bf16 bits
    const float* __restrict__ bias,         // [Ldim]
    float* __restrict__ C) {                // [Bdim][Ldim] fp32
  static_assert(NT >= 3, "pipeline needs >=3 K-tiles");
  __shared__ __align__(16) unsigned short lds[2][2][BM * BK];  // 128 KB

  const int tid = threadIdx.x;
  const int wave = tid >> 6;
  const int lane = tid & 63;
  const int wm = wave >> 2;   // 0..1  (M half)
  const int wn = wave & 3;    // 0..3  (N quarter)
  const int m_blk = blockIdx.y * BM;
  const int n_blk = blockIdx.x * BN;

  // staging source (pre-swizzled): wave covers rows [wave*8,+8) (+64 for 2nd GLL)
  const int srow = wave * 8 + (lane >> 3);
  const int skofs = ((lane & 7) ^ (lane >> 3)) * 8;
  const unsigned short* gA = A + (size_t)(m_blk + srow) * Hdim + skofs;
  const unsigned short* gB = Bw + (size_t)(n_blk + srow) * Hdim + skofs;

  // fragment read offsets (swizzled): row = base+fr, k 16B-slot = ksl*4+fq
  const int fr = lane & 15;
  const int fq = lane >> 4;
  const int kx0 = ((fq) ^ (fr & 7)) * 8;        // ksl=0
  const int kx1 = ((4 + fq) ^ (fr & 7)) * 8;    // ksl=1
  const int aBase = (wm * 128 + fr) * BK;
  const int bBase = (wn * 64 + fr) * BK;

  floatx4 acc[8][4] = {};
  bf16x8 af[8][2], bfv[4][2];

#define GLL(src, dst)                                                  \
  __builtin_amdgcn_global_load_lds(                                    \
      (const __attribute__((address_space(1))) void*)(src),            \
      (__attribute__((address_space(3))) void*)(dst), 16, 0, 0)

  // stage one half-tile (mat: 0=A 1=B, j: row-half) of K-tile kt into buf c
#define STAGE1(c, mat, j, kt)                                          \
  do {                                                                 \
    const unsigned short* _g = (mat) ? gB : gA;                        \
    GLL(_g + (size_t)((j) * 128) * Hdim + (size_t)(kt) * 64,           \
        &lds[c][mat][((j) * 128 + wave * 8) * BK]);                    \
    GLL(_g + (size_t)((j) * 128 + 64) * Hdim + (size_t)(kt) * 64,      \
        &lds[c][mat][((j) * 128 + 64 + wave * 8) * BK]);               \
  } while (0)

#define READ_A(c, lo)                                                  \
  do {                                                                 \
    _Pragma("unroll") for (int mi = (lo); mi < (lo) + 4; ++mi) {       \
      af[mi][0] = *(const bf16x8*)&lds[c][0][aBase + mi * 16 * BK + kx0]; \
      af[mi][1] = *(const bf16x8*)&lds[c][0][aBase + mi * 16 * BK + kx1]; \
    }                                                                  \
  } while (0)

#define READ_B(c, lo)                                                  \
  do {                                                                 \
    _Pragma("unroll") for (int ni = (lo); ni < (lo) + 2; ++ni) {       \
      bfv[ni][0] = *(const bf16x8*)&lds[c][1][bBase + ni * 16 * BK + kx0]; \
      bfv[ni][1] = *(const bf16x8*)&lds[c][1][bBase + ni * 16 * BK + kx1]; \
    }                                                                  \
  } while (0)

  // one C-quadrant (4 mi x 2 ni x 2 ksl = 16 MFMA), setprio-wrapped (T5)
#define MFMA_Q(M0, N0)                                                 \
  do {                                                                 \
    __builtin_amdgcn_s_setprio(1);                                     \
    _Pragma("unroll") for (int mi = (M0); mi < (M0) + 4; ++mi)         \
      _Pragma("unroll") for (int ni = (N0); ni < (N0) + 2; ++ni) {     \
        acc[mi][ni] = __builtin_amdgcn_mfma_f32_16x16x32_bf16(         \
            af[mi][0], bfv[ni][0], acc[mi][ni], 0, 0, 0);              \
        acc[mi][ni] = __builtin_amdgcn_mfma_f32_16x16x32_bf16(         \
            af[mi][1], bfv[ni][1], acc[mi][ni], 0, 0, 0);              \
      }                                                                \
    __builtin_amdgcn_s_setprio(0);                                     \
  } while (0)

#define BAR __builtin_amdgcn_s_barrier()
#define LGKM0 asm volatile("s_waitcnt lgkmcnt(0)" ::: "memory")

  // prologue: tile 0 fully + tile 1 A-half0; gate tile 0 (leave 2 in flight)
  STAGE1(0, 0, 0, 0);
  STAGE1(0, 0, 1, 0);
  STAGE1(0, 1, 0, 0);
  STAGE1(0, 1, 1, 0);
  STAGE1(1, 0, 0, 1);
  asm volatile("s_waitcnt vmcnt(2)\n\ts_barrier" ::: "memory");

#pragma unroll 1
  for (int t = 0; t < NT - 1; ++t) {
    const int c = t & 1;
    // ---- q0: quadrant (0,0); buf c gated by previous tile's q3
    STAGE1(c ^ 1, 0, 1, t + 1);   // A-h1(t+1)
    STAGE1(c ^ 1, 1, 0, t + 1);   // B-h0(t+1)
    READ_A(c, 0);
    READ_B(c, 0);
    BAR;
    LGKM0;
    MFMA_Q(0, 0);
    BAR;
    // ---- q1: quadrant (4,0)
    STAGE1(c ^ 1, 1, 1, t + 1);   // B-h1(t+1)
    READ_A(c, 4);
    BAR;
    LGKM0;
    MFMA_Q(4, 0);
    BAR;
    // ---- q2: quadrant (0,2) -- last reads of buf c
    READ_B(c, 2);
    BAR;
    LGKM0;
    MFMA_Q(0, 2);
    BAR;
    // ---- q3: quadrant (4,2); buf c now LDS-read-free -> stage t+2 into it
    if (t < NT - 2) {
      STAGE1(c, 0, 0, t + 2);     // A-h0(t+2)
      asm volatile("s_waitcnt vmcnt(2)\n\ts_barrier" ::: "memory");
    } else {
      asm volatile("s_waitcnt vmcnt(0)\n\ts_barrier" ::: "memory");
    }
    MFMA_Q(4, 2);
    BAR;
  }

  // tail: tile NT-1 (buf 1), fully gated; nothing left to stage
  READ_A(1, 0);
  READ_B(1, 0);
  READ_A(1, 4);
  READ_B(1, 2);
  LGKM0;
  MFMA_Q(0, 0);
  MFMA_Q(4, 0);
  MFMA_Q(0, 2);
  MFMA_Q(4, 2);

#undef GLL
#undef STAGE1
#undef READ_A
#undef READ_B
#undef MFMA_Q
#undef BAR
#undef LGKM0

  // epilogue: C/D layout col=lane&15, row=(lane>>4)*4+reg  [m89-verified]
  const int col0 = n_blk + wn * 64 + fr;
  const int row0 = m_blk + wm * 128 + fq * 4;
#pragma unroll
  for (int ni = 0; ni < 4; ++ni) {
    const float bs = bias[col0 + ni * 16];
#pragma unroll
    for (int mi = 0; mi < 8; ++mi) {
      float* cp = C + (size_t)(row0 + mi * 16) * Ldim + (col0 + ni * 16);
      floatx4 v = acc[mi][ni];
      cp[0 * (size_t)Ldim] = v.x + bs;
      cp[1 * (size_t)Ldim] = v.y + bs;
      cp[2 * (size_t)Ldim] = v.z + bs;
      cp[3 * (size_t)Ldim] = v.w + bs;
    }
  }
}

extern "C" void kernel_launch(void* const* d_in, const int* in_sizes, int n_in,
                              void* d_out, int out_size, void* d_ws, size_t ws_size,
                              hipStream_t stream) {
  const float* X = (const float*)d_in[0];  // bert_output [B,H]
  const float* E = (const float*)d_in[1];  // label_embed [L,H]
  const float* W = (const float*)d_in[2];  // W [L,H]
  const float* b = (const float*)d_in[3];  // b [L]
  // d_in[4] = labels, unused by the reference output.
  float* out = (float*)d_out;

  unsigned short* Xb = (unsigned short*)d_ws;                 // 8 MB
  unsigned short* Wb = Xb + (size_t)Bdim * Hdim;              // 8 MB
  float* bias = (float*)(Wb + (size_t)Ldim * Hdim);           // 16 KB

  prep_kernel<<<Ldim + Bdim, 256, 0, stream>>>(X, E, W, b, Xb, Wb, bias);
  dim3 grid(Ldim / BN, Bdim / BM);
  gemm_bias_kernel<<<grid, 512, 0, stream>>>(Xb, Wb, bias, out);
}

// Round 3
// 54.673 us; speedup vs baseline: 1.0204x; 1.0204x over previous
//
#include <hip/hip_runtime.h>
#include <hip/hip_bf16.h>

#define Bdim 4096
#define Ldim 4096
#define Hdim 1024
#define BM 256
#define BN 128
#define BK 32
#define NT (Hdim / BK)   // 32 K-tiles
#define SLOT_B 8192      // elems: A tile = 256*32
#define SLOT_E 12288     // + B tile 128*32  (24 KB/slot)

typedef __attribute__((ext_vector_type(8))) __bf16 bf16x8;
typedef __attribute__((ext_vector_type(4))) float floatx4;

__device__ __forceinline__ unsigned short f2bf(float f) {
  union { __hip_bfloat16 h; unsigned short u; } c;
  c.h = __float2bfloat16(f);
  return c.u;
}

// ---- fused prep: blocks [0,Ldim) do W->bf16 + bias row; [Ldim,+Bdim) X->bf16
__global__ __launch_bounds__(256) void prep_kernel(
    const float* __restrict__ X, const float* __restrict__ E,
    const float* __restrict__ W, const float* __restrict__ b,
    unsigned short* __restrict__ Xb, unsigned short* __restrict__ Wb,
    float* __restrict__ bias) {
  const int blk = blockIdx.x;
  const int t = threadIdx.x;
  if (blk < Ldim) {
    const int row = blk;
    const float4 wv = reinterpret_cast<const float4*>(W + (size_t)row * Hdim)[t];
    const float4 ev = reinterpret_cast<const float4*>(E + (size_t)row * Hdim)[t];
    ushort4 o;
    o.x = f2bf(wv.x); o.y = f2bf(wv.y); o.z = f2bf(wv.z); o.w = f2bf(wv.w);
    reinterpret_cast<ushort4*>(Wb + (size_t)row * Hdim)[t] = o;
    float dot = wv.x * ev.x + wv.y * ev.y + wv.z * ev.z + wv.w * ev.w;
#pragma unroll
    for (int off = 32; off > 0; off >>= 1) dot += __shfl_down(dot, off, 64);
    __shared__ float part[4];
    if ((t & 63) == 0) part[t >> 6] = dot;
    __syncthreads();
    if (t == 0) bias[row] = part[0] + part[1] + part[2] + part[3] + b[row];
  } else {
    const int i = (blk - Ldim) * 256 + t;
    float4 v = reinterpret_cast<const float4*>(X)[i];
    ushort4 o;
    o.x = f2bf(v.x); o.y = f2bf(v.y); o.z = f2bf(v.z); o.w = f2bf(v.w);
    reinterpret_cast<ushort4*>(Xb)[i] = o;
  }
}

// ---- C[B,L] = Xb @ Wb^T + bias -----------------------------------------
// 256x128 tile, BK=32, 8 waves (4M x 2N, each owns 64x64), grid 512 ->
// TWO blocks resident per CU (LDS 72 KB, regs <=128). Rationale (R2
// post-mortem): with 1 block/CU every barrier + the 10us C-write tail
// stalls the whole CU; a second independent block fills both.
// Schedule = R1's proven ring-3: one {vmcnt(3); s_barrier} per K-tile,
// stage kt+2 after the barrier (its slot was read at kt-1, all waves past
// that point => safe), 16 MFMAs. Gate leaves the newest stage (3 GLLs) in
// flight -- never vmcnt(0) mid-loop. Stage->use distance = 2 iterations.
// LDS swizzle (64B rows): k 16B-slot ks of row r stored at ks ^ ((r>>1)&3);
// GLL dest linear, global SOURCE pre-swizzled (row = tid>>2 under the GLL
// lane pattern => XOR term (tid>>3)&3); reads apply the same XOR. Residual
// 2-way bank aliasing only (free, m136).
// XCD chunking: 512 wgs = 8 XCDs x 64; chunk = 2 M-rows x 32 N-cols,
// m-fastest => A-panels (1 MB) stay in the XCD's L2, B reused x2.
__global__ __launch_bounds__(512, 4) void gemm_bias_kernel(
    const unsigned short* __restrict__ A,   // [Bdim][Hdim] bf16 bits
    const unsigned short* __restrict__ Bw,  // [Ldim][Hdim] bf16 bits
    const float* __restrict__ bias,         // [Ldim]
    float* __restrict__ C) {                // [Bdim][Ldim] fp32
  __shared__ __align__(16) unsigned short ring[3][SLOT_E];  // 72 KB

  const int tid = threadIdx.x;
  const int wave = tid >> 6;
  const int lane = tid & 63;
  const int wm = wave >> 1;   // 0..3 (M quarter, 64 rows)
  const int wn = wave & 1;    // 0..1 (N half, 64 cols)

  // XCD-chunked bijective swizzle (512 % 8 == 0)
  const int bid = blockIdx.x;
  const int xcd = bid & 7;
  const int idx = bid >> 3;                 // 0..63 within chunk
  const int m_blk = (xcd * 2 + (idx & 1)) * BM;
  const int n_blk = (idx >> 1) * BN;

  // staging source (pre-swizzled): thread covers row tid>>2, k-slot tid&3
  const int sr = tid >> 2;                  // 0..127
  const int skofs = ((tid & 3) ^ ((tid >> 3) & 3)) * 8;
  const unsigned short* gA0 = A + (size_t)(m_blk + sr) * Hdim + skofs;
  const unsigned short* gA1 = A + (size_t)(m_blk + 128 + sr) * Hdim + skofs;
  const unsigned short* gB0 = Bw + (size_t)(n_blk + sr) * Hdim + skofs;

  // fragment read offsets (swizzled): row = base + fr, k-elems = kx
  const int fr = lane & 15;
  const int fq = lane >> 4;
  const int kx = (fq ^ ((fr >> 1) & 3)) * 8;
  const int aofs = (wm * 64 + fr) * BK + kx;            // + mi*16*BK
  const int bofs = SLOT_B + (wn * 64 + fr) * BK + kx;   // + ni*16*BK

  floatx4 acc[4][4] = {};

#define GLL(src, dst)                                                  \
  __builtin_amdgcn_global_load_lds(                                    \
      (const __attribute__((address_space(1))) void*)(src),            \
      (__attribute__((address_space(3))) void*)(dst), 16, 0, 0)

#define STAGE(s, kt)                                                   \
  do {                                                                 \
    GLL(gA0 + (size_t)(kt) * BK, &ring[s][tid * 8]);                   \
    GLL(gA1 + (size_t)(kt) * BK, &ring[s][4096 + tid * 8]);            \
    GLL(gB0 + (size_t)(kt) * BK, &ring[s][SLOT_B + tid * 8]);          \
  } while (0)

#define COMPUTE(s)                                                     \
  do {                                                                 \
    bf16x8 af[4], bfv[4];                                              \
    _Pragma("unroll")                                                  \
    for (int i = 0; i < 4; ++i) {                                      \
      af[i]  = *(const bf16x8*)&ring[s][aofs + i * 16 * BK];           \
      bfv[i] = *(const bf16x8*)&ring[s][bofs + i * 16 * BK];           \
    }                                                                  \
    _Pragma("unroll")                                                  \
    for (int mi = 0; mi < 4; ++mi)                                     \
      _Pragma("unroll")                                                \
      for (int ni = 0; ni < 4; ++ni)                                   \
        acc[mi][ni] = __builtin_amdgcn_mfma_f32_16x16x32_bf16(         \
            af[mi], bfv[ni], acc[mi][ni], 0, 0, 0);                    \
  } while (0)

#define WAIT3_BAR asm volatile("s_waitcnt vmcnt(3)\n\ts_barrier" ::: "memory")
#define WAIT0_BAR asm volatile("s_waitcnt vmcnt(0)\n\ts_barrier" ::: "memory")

  STAGE(0, 0);   // 3 GLLs in flight
  STAGE(1, 1);   // 6 in flight

#pragma unroll 1
  for (int kt = 0; kt < 30; kt += 3) {
    WAIT3_BAR;            // stage kt done (all waves); kt+1 in flight
    STAGE(2, kt + 2);
    COMPUTE(0);           // tile kt
    WAIT3_BAR;            // stage kt+1 done; kt+2 in flight
    STAGE(0, kt + 3);
    COMPUTE(1);           // tile kt+1
    WAIT3_BAR;            // stage kt+2 done; kt+3 in flight
    STAGE(1, kt + 4);
    COMPUTE(2);           // tile kt+2
  }
  // staged: ..., 30 -> slot0, 31 -> slot1
  WAIT3_BAR;              // stage 30 done; 31 in flight
  COMPUTE(0);             // tile 30
  WAIT0_BAR;              // stage 31 done
  COMPUTE(1);             // tile 31

#undef GLL
#undef STAGE
#undef COMPUTE
#undef WAIT3_BAR
#undef WAIT0_BAR

  // epilogue: C/D layout col=lane&15, row=(lane>>4)*4+reg  [m89-verified]
  const int col0 = n_blk + wn * 64 + fr;
  const int row0 = m_blk + wm * 64 + fq * 4;
#pragma unroll
  for (int ni = 0; ni < 4; ++ni) {
    const float bs = bias[col0 + ni * 16];
#pragma unroll
    for (int mi = 0; mi < 4; ++mi) {
      float* cp = C + (size_t)(row0 + mi * 16) * Ldim + (col0 + ni * 16);
      floatx4 v = acc[mi][ni];
      cp[0 * (size_t)Ldim] = v.x + bs;
      cp[1 * (size_t)Ldim] = v.y + bs;
      cp[2 * (size_t)Ldim] = v.z + bs;
      cp[3 * (size_t)Ldim] = v.w + bs;
    }
  }
}

extern "C" void kernel_launch(void* const* d_in, const int* in_sizes, int n_in,
                              void* d_out, int out_size, void* d_ws, size_t ws_size,
                              hipStream_t stream) {
  const float* X = (const float*)d_in[0];  // bert_output [B,H]
  const float* E = (const float*)d_in[1];  // label_embed [L,H]
  const float* W = (const float*)d_in[2];  // W [L,H]
  const float* b = (const float*)d_in[3];  // b [L]
  // d_in[4] = labels, unused by the reference output.
  float* out = (float*)d_out;

  unsigned short* Xb = (unsigned short*)d_ws;                 // 8 MB
  unsigned short* Wb = Xb + (size_t)Bdim * Hdim;              // 8 MB
  float* bias = (float*)(Wb + (size_t)Ldim * Hdim);           // 16 KB

  prep_kernel<<<Ldim + Bdim, 256, 0, stream>>>(X, E, W, b, Xb, Wb, bias);
  gemm_bias_kernel<<<(Bdim / BM) * (Ldim / BN), 512, 0, stream>>>(Xb, Wb, bias, out);
}

// Round 5
// 50.233 us; speedup vs baseline: 1.1106x; 1.0884x over previous
//
#include <hip/hip_runtime.h>
#include <hip/hip_bf16.h>

#define Bdim 4096
#define Ldim 4096
#define Hdim 1024
#define BM 256
#define BN 256
#define BK 64
#define NT (Hdim / BK)   // 16 K-tiles

typedef __attribute__((ext_vector_type(8))) __bf16 bf16x8;
typedef __attribute__((ext_vector_type(4))) float floatx4;

__device__ __forceinline__ unsigned short f2bf(float f) {
  union { __hip_bfloat16 h; unsigned short u; } c;
  c.h = __float2bfloat16(f);
  return c.u;
}

// ---- fused prep: blocks [0,Ldim) do W->bf16 + bias row; [Ldim,+Bdim) X->bf16
__global__ __launch_bounds__(256) void prep_kernel(
    const float* __restrict__ X, const float* __restrict__ E,
    const float* __restrict__ W, const float* __restrict__ b,
    unsigned short* __restrict__ Xb, unsigned short* __restrict__ Wb,
    float* __restrict__ bias) {
  const int blk = blockIdx.x;
  const int t = threadIdx.x;
  if (blk < Ldim) {
    const int row = blk;
    const float4 wv = reinterpret_cast<const float4*>(W + (size_t)row * Hdim)[t];
    const float4 ev = reinterpret_cast<const float4*>(E + (size_t)row * Hdim)[t];
    ushort4 o;
    o.x = f2bf(wv.x); o.y = f2bf(wv.y); o.z = f2bf(wv.z); o.w = f2bf(wv.w);
    reinterpret_cast<ushort4*>(Wb + (size_t)row * Hdim)[t] = o;
    float dot = wv.x * ev.x + wv.y * ev.y + wv.z * ev.z + wv.w * ev.w;
#pragma unroll
    for (int off = 32; off > 0; off >>= 1) dot += __shfl_down(dot, off, 64);
    __shared__ float part[4];
    if ((t & 63) == 0) part[t >> 6] = dot;
    __syncthreads();
    if (t == 0) bias[row] = part[0] + part[1] + part[2] + part[3] + b[row];
  } else {
    const int i = (blk - Ldim) * 256 + t;
    float4 v = reinterpret_cast<const float4*>(X)[i];
    ushort4 o;
    o.x = f2bf(v.x); o.y = f2bf(v.y); o.z = f2bf(v.z); o.w = f2bf(v.w);
    reinterpret_cast<ushort4*>(Xb)[i] = o;
  }
}

// ---- C[B,L] = Xb @ Wb^T + bias -----------------------------------------
// 256x256, BK=64, 8 waves (2M x 4N, 128x64 each). m201-cadence 4-phase/tile:
// each phase = { stage ONE half-tile (2 GLL) ; ds_reads (12/8/4/0) ;
//                BAR ; lgkm0 ; setprio1 ; 16 MFMA ; setprio0 ; [BAR] }.
// Stage stream (strictly one half-tile/phase; A runs a full tile ahead of B):
//   tile t (buf c=t&1, o=c^1): P0: Bh0(t+1)->o   P1: Bh1(t+1)->o
//                              P2: Ah0(t+2)->c   P3: Ah1(t+2)->c
// Coverage (R4 bugfix): B(t+1) staged for t=0..14 -> B tiles 1..15 ALL
// staged (R4's DO_B=0 at tile 14 left tile 15 computing A(15)*B(13);
// absmax 1.36 == 5.5 sigma of sqrt(128)*0.02 -- fully explained).
// Legality (WAR): buf-c A region read-free after P1's post-MFMA barrier
// (each wave's LGKM0 precedes it) -> P2/P3 stage into c.A safe. buf-o B
// region last read at t-1's P2, certified by t-1 P3's gate barrier ->
// P0/P1 stages safe.
// Gate (T4): once per tile at P3: vmcnt(4)+barrier. Outstanding there =
// {A(t+1)[4], B(t+1)[4], A(t+2)[4]} = 12; wait to 4 retires all of t+1,
// leaves A(t+2) in flight. Newest retired load issued 2 phases earlier.
// Tile 14: outstanding = A(15)[4]+B(15)[4] -> GATE0 drains (B(15) issued
// 2 phases before). Tile 15: no stage, no gate. Never vmcnt(0) mid-loop.
// LDS swizzle (T2, conflicts=0 measured R1/R2): 16B-slot ks of row r at
// ks ^ (r&7); GLL dest linear, global SOURCE pre-swizzled, reads same XOR.
__global__ __launch_bounds__(512, 2) void gemm_bias_kernel(
    const unsigned short* __restrict__ A,   // [Bdim][Hdim] bf16 bits
    const unsigned short* __restrict__ Bw,  // [Ldim][Hdim] bf16 bits
    const float* __restrict__ bias,         // [Ldim]
    float* __restrict__ C) {                // [Bdim][Ldim] fp32
  __shared__ __align__(16) unsigned short lds[2][2][BM * BK];  // 128 KB

  const int tid = threadIdx.x;
  const int wave = tid >> 6;
  const int lane = tid & 63;
  const int wm = wave >> 2;   // 0..1  (M half)
  const int wn = wave & 3;    // 0..3  (N quarter)
  const int m_blk = blockIdx.y * BM;
  const int n_blk = blockIdx.x * BN;

  // staging source (pre-swizzled): wave covers rows [wave*8,+8) per GLL
  const int srow = wave * 8 + (lane >> 3);
  const int skofs = ((lane & 7) ^ (lane >> 3)) * 8;
  const unsigned short* gA = A + (size_t)(m_blk + srow) * Hdim + skofs;
  const unsigned short* gB = Bw + (size_t)(n_blk + srow) * Hdim + skofs;

  // fragment read offsets (swizzled): row = base+fr, k 16B-slot = ksl*4+fq
  const int fr = lane & 15;
  const int fq = lane >> 4;
  const int kx0 = ((fq) ^ (fr & 7)) * 8;        // k 0..31
  const int kx1 = ((4 + fq) ^ (fr & 7)) * 8;    // k 32..63
  const int aBase = (wm * 128 + fr) * BK;
  const int bBase = (wn * 64 + fr) * BK;

  floatx4 acc[8][4] = {};
  bf16x8 af[8][2], bfv[4][2];

#define GLL(src, dst)                                                  \
  __builtin_amdgcn_global_load_lds(                                    \
      (const __attribute__((address_space(1))) void*)(src),            \
      (__attribute__((address_space(3))) void*)(dst), 16, 0, 0)

  // stage one half-tile (mat 0=A 1=B, h = row-half) of K-tile kt into buf c
#define STAGE_H(c, mat, h, kt)                                         \
  do {                                                                 \
    const unsigned short* _g = (mat) ? gB : gA;                        \
    GLL(_g + (size_t)((h) * 128) * Hdim + (size_t)(kt) * BK,           \
        &lds[c][mat][((h) * 128 + wave * 8) * BK]);                    \
    GLL(_g + (size_t)((h) * 128 + 64) * Hdim + (size_t)(kt) * BK,      \
        &lds[c][mat][((h) * 128 + 64 + wave * 8) * BK]);               \
  } while (0)

#define READ_A(c, lo)                                                  \
  do {                                                                 \
    _Pragma("unroll") for (int mi = (lo); mi < (lo) + 4; ++mi) {       \
      af[mi][0] = *(const bf16x8*)&lds[c][0][aBase + mi * 16 * BK + kx0]; \
      af[mi][1] = *(const bf16x8*)&lds[c][0][aBase + mi * 16 * BK + kx1]; \
    }                                                                  \
  } while (0)

#define READ_B(c, lo)                                                  \
  do {                                                                 \
    _Pragma("unroll") for (int ni = (lo); ni < (lo) + 2; ++ni) {       \
      bfv[ni][0] = *(const bf16x8*)&lds[c][1][bBase + ni * 16 * BK + kx0]; \
      bfv[ni][1] = *(const bf16x8*)&lds[c][1][bBase + ni * 16 * BK + kx1]; \
    }                                                                  \
  } while (0)

#define MFMA_Q(M0, N0)                                                 \
  do {                                                                 \
    __builtin_amdgcn_s_setprio(1);                                     \
    _Pragma("unroll") for (int mi = (M0); mi < (M0) + 4; ++mi)         \
      _Pragma("unroll") for (int ni = (N0); ni < (N0) + 2; ++ni) {     \
        acc[mi][ni] = __builtin_amdgcn_mfma_f32_16x16x32_bf16(         \
            af[mi][0], bfv[ni][0], acc[mi][ni], 0, 0, 0);              \
        acc[mi][ni] = __builtin_amdgcn_mfma_f32_16x16x32_bf16(         \
            af[mi][1], bfv[ni][1], acc[mi][ni], 0, 0, 0);              \
      }                                                                \
    __builtin_amdgcn_s_setprio(0);                                     \
  } while (0)

#define BAR __builtin_amdgcn_s_barrier()
#define LGKM0 asm volatile("s_waitcnt lgkmcnt(0)" ::: "memory")
#define GATE4 asm volatile("s_waitcnt vmcnt(4)\n\ts_barrier" ::: "memory")
#define GATE0 asm volatile("s_waitcnt vmcnt(0)\n\ts_barrier" ::: "memory")

  // DO_B: stage B(kt+1)->o at P0/P1.  DO_A: stage A(kt+2)->c at P2/P3.
#define TILE_BODY(c, o, kt, DO_B, DO_A, GATE)                          \
  do {                                                                 \
    /* P0 */                                                           \
    if (DO_B) STAGE_H(o, 1, 0, (kt) + 1);                              \
    READ_A(c, 0);                                                      \
    READ_B(c, 0);                                                      \
    BAR; LGKM0;                                                        \
    MFMA_Q(0, 0);                                                      \
    /* P1 */                                                           \
    if (DO_B) STAGE_H(o, 1, 1, (kt) + 1);                              \
    READ_A(c, 4);                                                      \
    BAR; LGKM0;                                                        \
    MFMA_Q(4, 0);                                                      \
    BAR;  /* collective: all af reads of buf c complete -> c.A free */ \
    /* P2 */                                                           \
    if (DO_A) STAGE_H(c, 0, 0, (kt) + 2);                              \
    READ_B(c, 2);                                                      \
    BAR; LGKM0;                                                        \
    MFMA_Q(0, 2);                                                      \
    BAR;  /* collective: all reads of buf c complete */                \
    /* P3 */                                                           \
    if (DO_A) STAGE_H(c, 0, 1, (kt) + 2);                              \
    GATE;                                                              \
    MFMA_Q(4, 2);                                                      \
  } while (0)

  // prologue: tile 0 fully + tile 1 A halves (12 GLLs), gate to 4
  STAGE_H(0, 0, 0, 0);
  STAGE_H(0, 0, 1, 0);
  STAGE_H(0, 1, 0, 0);
  STAGE_H(0, 1, 1, 0);
  STAGE_H(1, 0, 0, 1);
  STAGE_H(1, 0, 1, 1);
  GATE4;

#pragma unroll 1
  for (int t = 0; t < NT - 2; t += 2) {
    TILE_BODY(0, 1, t, 1, 1, GATE4);
    TILE_BODY(1, 0, t + 1, 1, 1, GATE4);
  }
  // tile NT-2 (buf 0): STILL stages B(NT-1)->buf1 (R4 bugfix); no A stage;
  // GATE0 drains A(15)+B(15) (B(15) issued 2 phases earlier).
  TILE_BODY(0, 1, NT - 2, 1, 0, GATE0);
  // tile NT-1 (buf 1): all data resident & retired; no stages, no gate.
  TILE_BODY(1, 0, NT - 1, 0, 0, (void)0);

#undef GLL
#undef STAGE_H
#undef READ_A
#undef READ_B
#undef MFMA_Q
#undef BAR
#undef LGKM0
#undef GATE4
#undef GATE0
#undef TILE_BODY

  // epilogue: C/D layout col=lane&15, row=(lane>>4)*4+reg  [m89-verified]
  const int col0 = n_blk + wn * 64 + fr;
  const int row0 = m_blk + wm * 128 + fq * 4;
#pragma unroll
  for (int ni = 0; ni < 4; ++ni) {
    const float bs = bias[col0 + ni * 16];
#pragma unroll
    for (int mi = 0; mi < 8; ++mi) {
      float* cp = C + (size_t)(row0 + mi * 16) * Ldim + (col0 + ni * 16);
      floatx4 v = acc[mi][ni];
      cp[0 * (size_t)Ldim] = v.x + bs;
      cp[1 * (size_t)Ldim] = v.y + bs;
      cp[2 * (size_t)Ldim] = v.z + bs;
      cp[3 * (size_t)Ldim] = v.w + bs;
    }
  }
}

extern "C" void kernel_launch(void* const* d_in, const int* in_sizes, int n_in,
                              void* d_out, int out_size, void* d_ws, size_t ws_size,
                              hipStream_t stream) {
  const float* X = (const float*)d_in[0];  // bert_output [B,H]
  const float* E = (const float*)d_in[1];  // label_embed [L,H]
  const float* W = (const float*)d_in[2];  // W [L,H]
  const float* b = (const float*)d_in[3];  // b [L]
  // d_in[4] = labels, unused by the reference output.
  float* out = (float*)d_out;

  unsigned short* Xb = (unsigned short*)d_ws;                 // 8 MB
  unsigned short* Wb = Xb + (size_t)Bdim * Hdim;              // 8 MB
  float* bias = (float*)(Wb + (size_t)Ldim * Hdim);           // 16 KB

  prep_kernel<<<Ldim + Bdim, 256, 0, stream>>>(X, E, W, b, Xb, Wb, bias);
  dim3 grid(Ldim / BN, Bdim / BM);
  gemm_bias_kernel<<<grid, 512, 0, stream>>>(Xb, Wb, bias, out);
}